// Round 5
// baseline (6393.189 us; speedup 1.0000x reference)
//
#include <hip/hip_runtime.h>

// Dims
constexpr int TSTEPS = 512;
constexpr int FDIM   = 128;
constexpr int HDIM   = 256;
constexpr int G4H    = 1024;   // 4*H
constexpr int BATCH  = 256;
constexpr int NB     = 86;     // 84 blocks x 3 rows + 2 blocks x 2 rows

typedef float    f32x4 __attribute__((ext_vector_type(4)));
typedef _Float16 f16x4 __attribute__((ext_vector_type(4)));

constexpr size_t W16_FULL = (size_t)(HDIM + FDIM) * G4H * 2;  // 768 KB: rker+kern fp16
constexpr size_t W16_RK   = (size_t)HDIM * G4H * 2;           // 512 KB: rker only (<= proven ws floor 525KB)

__device__ __forceinline__ float sigmf(float z) { return 1.f / (1.f + __expf(-z)); }
__device__ __forceinline__ float tanhf_fast(float z) {
    float a = fabsf(z);
    float e = __expf(-2.f * a);
    float r = (1.f - e) / (1.f + e);
    return z < 0.f ? -r : r;
}

// fp32 -> fp16 weight conversion (RTNE). Layout: w16[k][c], k<256 = rker, k>=256 = kern.
extern "C" __global__ void __launch_bounds__(256)
conv_w16(const float* __restrict__ kern, const float* __restrict__ rker,
         _Float16* __restrict__ w16, int nrows)
{
    const int total = nrows * G4H;
    for (int i = blockIdx.x * 256 + threadIdx.x; i < total; i += gridDim.x * 256) {
        const int k = i >> 10, c = i & 1023;
        const float v = (k < HDIM) ? rker[(size_t)k * G4H + c]
                                   : kern[(size_t)(k - HDIM) * G4H + c];
        w16[i] = (_Float16)v;
    }
}

// Zero-sync LSTM, fp16-weight stream. Round-4 analysis: binding constraint is the
// per-CU vector-load port (~60 B/cyc); fp32 weights = 1.5 MB/step/CU = 9.8us floor.
// fp16 halves bytes -> ~5.3us/step. h/x/accum stay fp32 (output err ~1e-4 << 1.68e-3).
// 86 blocks x 1024 threads (16 waves: quarter=wave>>2 splits K 4-way, gate=wave&3).
// Thread owns 4 consecutive columns of its gate. Head (relu-MLP) fused at the end.
template <bool K16>  // true: kern also fp16 in w16; false: kern streamed fp32
__global__ __launch_bounds__(1024, 1) void
lstm_f16(const float* __restrict__ x, const _Float16* __restrict__ w16,
         const float* __restrict__ kern, const float* __restrict__ w1,
         const float* __restrict__ b1, const float* __restrict__ w2,
         const float* __restrict__ b2, float* __restrict__ out)
{
    const int b    = blockIdx.x;
    const int base = (b < 84) ? 3 * b : 252 + 2 * (b - 84);
    const int nval = (b < 84) ? 3 : 2;
    const int tid  = threadIdx.x;
    const int wave = tid >> 6;
    const int lane = tid & 63;
    const int q    = wave >> 2;               // K quarter: k in [96q, 96q+96)
    const int gate = wave & 3;                // i,f,g,o
    const int coff = gate * 256 + lane * 4;   // 4 consecutive columns

    __shared__ __align__(16) float hx[384 * 4];      // [k][row]: k<256 h, k>=256 x(t)
    __shared__ __align__(16) float zp[4][3][G4H];    // quarter partials, 48 KB
    __shared__ float hid[3][100];                    // fused-head hidden

    for (int i = tid; i < 384 * 4; i += 1024) hx[i] = 0.f;  // h(0)=0 (+pad row)

    // P2 mapping: tid<768 -> (r = tid>>8, u = tid&255); per-thread cell state
    const int rP = tid >> 8, uP = tid & 255;
    float cst = 0.f;

    // x staging: tid<384 -> row = tid>>7, f = tid&127 (512B coalesced per row)
    const int xr = tid >> 7, xf = tid & 127;
    const float* xptr = x + ((size_t)min(base + xr, BATCH - 1) * TSTEPS) * FDIM + xf;

    const _Float16* wp = w16 + coff;
    const int klo = q * 96, khi = klo + 96;
    const int k16hi = K16 ? khi : min(khi, HDIM);   // fp16 region end for this quarter

#pragma unroll 1
    for (int t = 0; t < TSTEPS; ++t) {
        // ---- P0: stage x(t)
        if (tid < 384)
            hx[(256 + xf) * 4 + xr] = xptr[(size_t)t * FDIM];
        __syncthreads();  // B1: x+h staged; zp(t-1) consumed

        // ---- P1: quarter GEMM. Per k: 8B fp16 load (L2) + broadcast ds_read_b128 + 12 FMA.
        f32x4 a0 = {0.f, 0.f, 0.f, 0.f}, a1 = a0, a2 = a0;
#pragma unroll 4
        for (int k = klo; k < k16hi; ++k) {
            const f16x4 w4 = *reinterpret_cast<const f16x4*>(wp + (size_t)k * G4H);
            const f32x4 hr = *reinterpret_cast<const f32x4*>(&hx[k * 4]);
            const float w0 = (float)w4[0], w1f = (float)w4[1],
                        w2f = (float)w4[2], w3 = (float)w4[3];
            a0[0] += hr[0] * w0; a0[1] += hr[0] * w1f; a0[2] += hr[0] * w2f; a0[3] += hr[0] * w3;
            a1[0] += hr[1] * w0; a1[1] += hr[1] * w1f; a1[2] += hr[1] * w2f; a1[3] += hr[1] * w3;
            a2[0] += hr[2] * w0; a2[1] += hr[2] * w1f; a2[2] += hr[2] * w2f; a2[3] += hr[2] * w3;
        }
        if constexpr (!K16) {  // fp32 kern tail (quarters 2,3)
#pragma unroll 4
            for (int k = max(klo, HDIM); k < khi; ++k) {
                const f32x4 w4 = *reinterpret_cast<const f32x4*>(
                    kern + (size_t)(k - HDIM) * G4H + coff);
                const f32x4 hr = *reinterpret_cast<const f32x4*>(&hx[k * 4]);
#pragma unroll
                for (int j = 0; j < 4; ++j) {
                    a0[j] += hr[0] * w4[j];
                    a1[j] += hr[1] * w4[j];
                    a2[j] += hr[2] * w4[j];
                }
            }
        }
        // Partials: lane-consecutive b128 stores, conflict-free
        *reinterpret_cast<f32x4*>(&zp[q][0][coff]) = a0;
        *reinterpret_cast<f32x4*>(&zp[q][1][coff]) = a1;
        *reinterpret_cast<f32x4*>(&zp[q][2][coff]) = a2;
        __syncthreads();  // B2

        // ---- P2: combine quarters, gates, cell update, h(t+1) -> hx
        if (tid < 768) {
            float z0 = 0.f, z1 = 0.f, z2 = 0.f, z3 = 0.f;
#pragma unroll
            for (int qq = 0; qq < 4; ++qq) {
                z0 += zp[qq][rP][0 * 256 + uP];
                z1 += zp[qq][rP][1 * 256 + uP];
                z2 += zp[qq][rP][2 * 256 + uP];
                z3 += zp[qq][rP][3 * 256 + uP];
            }
            cst = sigmf(z1) * cst + sigmf(z0) * tanhf_fast(z2);
            hx[uP * 4 + rP] = sigmf(z3) * tanhf_fast(cst);
        }
        // No barrier: B1(next) orders hx writes/zp reads vs next step.
    }
    __syncthreads();

    // ---- Fused head: out[row] = relu(h@w1+b1)@w2 + b2
    if (tid < 300) {
        const int r = tid / 100, j = tid - r * 100;
        if (r < nval) {
            float acc = b1[j];
#pragma unroll 8
            for (int k = 0; k < HDIM; ++k)
                acc += hx[k * 4 + r] * w1[k * 100 + j];
            hid[r][j] = fmaxf(acc, 0.f);
        }
    }
    __syncthreads();
    if (tid < 3 && tid < nval) {
        float v = b2[0];
#pragma unroll 4
        for (int j = 0; j < 100; ++j) v += hid[tid][j] * w2[j];
        out[base + tid] = v;
    }
}

extern "C" void kernel_launch(void* const* d_in, const int* in_sizes, int n_in,
                              void* d_out, int out_size, void* d_ws, size_t ws_size,
                              hipStream_t stream)
{
    const float* x    = (const float*)d_in[0];
    const float* kern = (const float*)d_in[1];
    const float* rker = (const float*)d_in[2];
    const float* w1   = (const float*)d_in[3];
    const float* b1   = (const float*)d_in[4];
    const float* w2   = (const float*)d_in[5];
    const float* b2   = (const float*)d_in[6];
    float* out = (float*)d_out;

    _Float16* w16 = (_Float16*)d_ws;
    // ws_size is fixed per-problem -> branch is identical every call (graph-safe).
    const bool full16 = ws_size >= W16_FULL;   // rounds 1-3 prove ws_size >= 525KB >= W16_RK
    const int  nrows  = full16 ? (HDIM + FDIM) : HDIM;

    conv_w16<<<dim3(512), dim3(256), 0, stream>>>(kern, rker, w16, nrows);
    if (full16)
        lstm_f16<true><<<dim3(NB), dim3(1024), 0, stream>>>(x, w16, kern, w1, b1, w2, b2, out);
    else
        lstm_f16<false><<<dim3(NB), dim3(1024), 0, stream>>>(x, w16, kern, w1, b1, w2, b2, out);
}